// Round 1
// baseline (101.004 us; speedup 1.0000x reference)
//
#include <hip/hip_runtime.h>
#include <hip/hip_bf16.h>

// Problem constants (fixed by reference): B=8, T=2048, C=64
#define B_ 8
#define T_ 2048
#define LOG2E 1.4426950408889634f

typedef _Float16 half8 __attribute__((ext_vector_type(8)));
typedef float f32x4 __attribute__((ext_vector_type(4)));

#define MFMA16(A, Bv, Cv) __builtin_amdgcn_mfma_f32_16x16x32_f16((A), (Bv), (Cv), 0, 0, 0)

// ---------------------------------------------------------------------------
// Kernel 1: pointwise projections. F [B*T,64] fp32 -> Qh,Kh [B*T,64] f16 and
// Vt [B][64][T] f16 (transposed so PV B-operand loads are contiguous).
// Block = 256 threads = 4 rows x 64 channels; one thread -> one (row,d), 3 outs.
// ---------------------------------------------------------------------------
__global__ __launch_bounds__(256) void proj_kernel(
    const float* __restrict__ F, const float* __restrict__ WM,
    const float* __restrict__ WN, const float* __restrict__ WV,
    _Float16* __restrict__ Qh, _Float16* __restrict__ Kh,
    _Float16* __restrict__ Vt)
{
    const int d    = threadIdx.x & 63;
    const int rsub = threadIdx.x >> 6;
    const int row  = blockIdx.x * 4 + rsub;      // [0, B*T)
    const int b    = row >> 11;                  // row / 2048
    const int t    = row & (T_ - 1);
    const float* frow = F + (size_t)row * 64;

    float am = 0.f, an = 0.f, av = 0.f;
#pragma unroll
    for (int k = 0; k < 64; ++k) {
        const float f = frow[k];                 // broadcast across the wave
        am = fmaf(f, WM[k * 64 + d], am);        // coalesced, L1-resident W
        an = fmaf(f, WN[k * 64 + d], an);
        av = fmaf(f, WV[k * 64 + d], av);
    }
    Qh[(size_t)row * 64 + d] = (_Float16)am;
    Kh[(size_t)row * 64 + d] = (_Float16)an;
    Vt[((size_t)b * 64 + d) * T_ + t] = (_Float16)av;
}

// pack two fp32 -> fp16x2 in a u32 (RNE via v_cvt_f16_f32)
__device__ inline unsigned pkh(float a, float b)
{
    union { _Float16 h[2]; unsigned u; } z;
    z.h[0] = (_Float16)a;
    z.h[1] = (_Float16)b;
    return z.u;
}

// ---------------------------------------------------------------------------
// Kernel 2: flash attention. Grid = B*T/64 = 256 blocks, 4 waves/block,
// each wave owns 16 q-rows and streams all 2048 keys in 32-key chunks.
// Swapped QK^T: S^T[kk][q] = mfma(A=K-frag, B=Q-frag); C layout (m89-verified)
// puts q = lane&15, kk = 4*(lane>>4)+reg -> row softmax needs only
// shfl_xor(16/32). P is packed to f16 and regrouped by 8 shuffles into the
// PV A-fragment (lane group g needs kk 8g..8g+7). K/V read from global (L2:
// 512 KB per batch). Accumulate O in fp32, residual added in epilogue.
// ---------------------------------------------------------------------------
__global__ __launch_bounds__(256) void attn_kernel(
    const _Float16* __restrict__ Qh, const _Float16* __restrict__ Kh,
    const _Float16* __restrict__ Vt, const float* __restrict__ F,
    float* __restrict__ out)
{
    const int lane = threadIdx.x & 63;
    const int wid  = threadIdx.x >> 6;
    const int blk  = blockIdx.x;                 // 0..255
    const int b    = blk >> 5;                   // 32 q-tiles per batch
    const int qbase = ((blk & 31) << 6) + (wid << 4); // q offset within batch
    const int ql = lane & 15;
    const int g  = lane >> 4;

    const _Float16* Qbb = Qh + (size_t)b * T_ * 64;
    const _Float16* Kbb = Kh + (size_t)b * T_ * 64;
    const _Float16* Vtb = Vt + (size_t)b * 64 * T_;

    // Q fragments (B operand): lane holds col q=ql, k(d) = 8g+j (+32 step 1)
    const half8* qp = (const half8*)(Qbb + (qbase + ql) * 64);
    const half8 qf0 = qp[g];
    const half8 qf1 = qp[4 + g];

    f32x4 acc0 = {0.f, 0.f, 0.f, 0.f};
    f32x4 acc1 = {0.f, 0.f, 0.f, 0.f};
    f32x4 acc2 = {0.f, 0.f, 0.f, 0.f};
    f32x4 acc3 = {0.f, 0.f, 0.f, 0.f};
    float m    = -1e30f;   // running max, base-2 domain
    float lsum = 0.f;

    // shuffle sources for the P regroup: dest (q,g) pulls kk 8g..8g+3 from
    // group (2g)&3 and kk 8g+4..8g+7 from group (2g+1)&3, tile = g>>1
    const int L0 = ql | (((2 * g) & 3) << 4);
    const int L1 = ql | (((2 * g + 1) & 3) << 4);
    const bool hi = (g >= 2);
    // redistribution sources: acc lane reg r holds row q=4g+r; fac/inv for
    // that q lives at any lane with lane&15 == 4g+r
    const int R0 = (lane & 48) | (4 * g + 0);
    const int R1 = (lane & 48) | (4 * g + 1);
    const int R2 = (lane & 48) | (4 * g + 2);
    const int R3 = (lane & 48) | (4 * g + 3);

    for (int kb = 0; kb < T_; kb += 32) {
        // ---- QK^T for two 16-key tiles (K = d in {0..31},{32..63}) ----
        const half8* kp0 = (const half8*)(Kbb + (kb + ql) * 64);
        const half8* kp1 = (const half8*)(Kbb + (kb + 16 + ql) * 64);
        f32x4 s0 = {0.f, 0.f, 0.f, 0.f};
        f32x4 s1 = {0.f, 0.f, 0.f, 0.f};
        s0 = MFMA16(kp0[g], qf0, s0);
        s0 = MFMA16(kp0[4 + g], qf1, s0);
        s1 = MFMA16(kp1[g], qf0, s1);
        s1 = MFMA16(kp1[4 + g], qf1, s1);

        // ---- online softmax (base 2). lane's 8 scores: tile0 kk=4g+r,
        //      tile1 kk=16+4g+r, all for q = ql ----
        float p0 = s0[0] * LOG2E, p1 = s0[1] * LOG2E;
        float p2 = s0[2] * LOG2E, p3 = s0[3] * LOG2E;
        float p4 = s1[0] * LOG2E, p5 = s1[1] * LOG2E;
        float p6 = s1[2] * LOG2E, p7 = s1[3] * LOG2E;

        float pm = fmaxf(fmaxf(fmaxf(p0, p1), fmaxf(p2, p3)),
                         fmaxf(fmaxf(p4, p5), fmaxf(p6, p7)));
        pm = fmaxf(pm, __shfl_xor(pm, 16));
        pm = fmaxf(pm, __shfl_xor(pm, 32));
        const float mnew = fmaxf(m, pm);
        const float fac  = exp2f(m - mnew);
        m = mnew;

        p0 = exp2f(p0 - mnew); p1 = exp2f(p1 - mnew);
        p2 = exp2f(p2 - mnew); p3 = exp2f(p3 - mnew);
        p4 = exp2f(p4 - mnew); p5 = exp2f(p5 - mnew);
        p6 = exp2f(p6 - mnew); p7 = exp2f(p7 - mnew);

        float psum = ((p0 + p1) + (p2 + p3)) + ((p4 + p5) + (p6 + p7));
        psum += __shfl_xor(psum, 16);
        psum += __shfl_xor(psum, 32);
        lsum = lsum * fac + psum;

        // ---- pack P to f16 pairs and regroup into PV A-fragment ----
        const unsigned t0a = pkh(p0, p1), t0b = pkh(p2, p3);
        const unsigned t1a = pkh(p4, p5), t1b = pkh(p6, p7);
        const unsigned x0a = (unsigned)__shfl((int)t0a, L0);
        const unsigned x1a = (unsigned)__shfl((int)t1a, L0);
        const unsigned x0b = (unsigned)__shfl((int)t0b, L0);
        const unsigned x1b = (unsigned)__shfl((int)t1b, L0);
        const unsigned y0a = (unsigned)__shfl((int)t0a, L1);
        const unsigned y1a = (unsigned)__shfl((int)t1a, L1);
        const unsigned y0b = (unsigned)__shfl((int)t0b, L1);
        const unsigned y1b = (unsigned)__shfl((int)t1b, L1);
        union { unsigned u[4]; half8 v; } pa;
        pa.u[0] = hi ? x1a : x0a;
        pa.u[1] = hi ? x1b : x0b;
        pa.u[2] = hi ? y1a : y0a;
        pa.u[3] = hi ? y1b : y0b;

        // ---- rescale accumulators (factor redistributed to acc layout) ----
        const float f0 = __shfl(fac, R0);
        const float f1 = __shfl(fac, R1);
        const float f2 = __shfl(fac, R2);
        const float f3 = __shfl(fac, R3);
        acc0[0] *= f0; acc0[1] *= f1; acc0[2] *= f2; acc0[3] *= f3;
        acc1[0] *= f0; acc1[1] *= f1; acc1[2] *= f2; acc1[3] *= f3;
        acc2[0] *= f0; acc2[1] *= f1; acc2[2] *= f2; acc2[3] *= f3;
        acc3[0] *= f0; acc3[1] *= f1; acc3[2] *= f2; acc3[3] *= f3;

        // ---- PV: B operand from Vt (contiguous kk per lane) ----
        const half8 v0 = *(const half8*)(Vtb + (0 * 16 + ql) * T_ + kb + g * 8);
        const half8 v1 = *(const half8*)(Vtb + (1 * 16 + ql) * T_ + kb + g * 8);
        const half8 v2 = *(const half8*)(Vtb + (2 * 16 + ql) * T_ + kb + g * 8);
        const half8 v3 = *(const half8*)(Vtb + (3 * 16 + ql) * T_ + kb + g * 8);
        acc0 = MFMA16(pa.v, v0, acc0);
        acc1 = MFMA16(pa.v, v1, acc1);
        acc2 = MFMA16(pa.v, v2, acc2);
        acc3 = MFMA16(pa.v, v3, acc3);
    }

    // ---- epilogue: divide by lsum, add residual, store fp32 ----
    const float inv = 1.0f / lsum;
    const float i0 = __shfl(inv, R0);
    const float i1 = __shfl(inv, R1);
    const float i2 = __shfl(inv, R2);
    const float i3 = __shfl(inv, R3);
    const float iv[4] = {i0, i1, i2, i3};

    const float* Fb = F + (size_t)b * T_ * 64;
    float* ob = out + (size_t)b * T_ * 64;
#pragma unroll
    for (int r = 0; r < 4; ++r) {
        const int trow = qbase + 4 * g + r;
        const int base = trow * 64 + ql;
        ob[base +  0] = acc0[r] * iv[r] + Fb[base +  0];
        ob[base + 16] = acc1[r] * iv[r] + Fb[base + 16];
        ob[base + 32] = acc2[r] * iv[r] + Fb[base + 32];
        ob[base + 48] = acc3[r] * iv[r] + Fb[base + 48];
    }
}

extern "C" void kernel_launch(void* const* d_in, const int* in_sizes, int n_in,
                              void* d_out, int out_size, void* d_ws, size_t ws_size,
                              hipStream_t stream)
{
    const float* F  = (const float*)d_in[0];
    const float* WM = (const float*)d_in[1];
    const float* WN = (const float*)d_in[2];
    const float* WV = (const float*)d_in[3];
    float* out = (float*)d_out;

    const size_t proj_bytes = (size_t)B_ * T_ * 64 * sizeof(_Float16); // 2 MB
    char* ws = (char*)d_ws;
    _Float16* Qh = (_Float16*)(ws);
    _Float16* Kh = (_Float16*)(ws + proj_bytes);
    _Float16* Vt = (_Float16*)(ws + 2 * proj_bytes);

    hipLaunchKernelGGL(proj_kernel, dim3(B_ * T_ / 4), dim3(256), 0, stream,
                       F, WM, WN, WV, Qh, Kh, Vt);
    hipLaunchKernelGGL(attn_kernel, dim3(B_ * T_ / 64), dim3(256), 0, stream,
                       Qh, Kh, Vt, F, out);
}

// Round 2
// 79.363 us; speedup vs baseline: 1.2727x; 1.2727x over previous
//
#include <hip/hip_runtime.h>
#include <hip/hip_bf16.h>

// Problem constants (fixed by reference): B=8, T=2048, C=64
#define B_ 8
#define T_ 2048
#define LOG2E 1.4426950408889634f

typedef _Float16 half8 __attribute__((ext_vector_type(8)));
typedef float f32x4 __attribute__((ext_vector_type(4)));

#define MFMA16(A, Bv, Cv) __builtin_amdgcn_mfma_f32_16x16x32_f16((A), (Bv), (Cv), 0, 0, 0)

// ---------------------------------------------------------------------------
// Kernel 0: pre-pack weights. W [k][d] fp32 -> Wp [mat][d][k] f16 so proj's
// MFMA B-fragments are contiguous half8 loads. One tiny block.
// ---------------------------------------------------------------------------
__global__ __launch_bounds__(256) void prepack_kernel(
    const float* __restrict__ WM, const float* __restrict__ WN,
    const float* __restrict__ WV, _Float16* __restrict__ Wp)
{
    const int t  = threadIdx.x;
    const int d  = t >> 2;
    const int kb = (t & 3) * 16;
    const float* Ws[3] = {WM, WN, WV};
#pragma unroll
    for (int m = 0; m < 3; ++m) {
        _Float16* dst = Wp + m * 4096 + d * 64;
        const float* src = Ws[m];
        for (int k = kb; k < kb + 16; ++k)
            dst[k] = (_Float16)src[k * 64 + d];
    }
}

// ---------------------------------------------------------------------------
// Kernel 1: MFMA projections. Each wave computes 16 rows x 64 cols for all
// three matrices: 24 mfma_16x16x32_f16. A-frag = F rows (fp32 load + cvt),
// B-frag = Wp cols (contiguous half8, L1-resident). C layout (m89): lane
// holds col d = dt*16 + (lane&15), rows t = 4*(lane>>4)+reg.
// Q,K stored row-major f16; V stored transposed Vt[b][d][t] f16.
// ---------------------------------------------------------------------------
__global__ __launch_bounds__(256) void proj_kernel(
    const float* __restrict__ F, const _Float16* __restrict__ Wp,
    _Float16* __restrict__ Qh, _Float16* __restrict__ Kh,
    _Float16* __restrict__ Vt)
{
    const int lane = threadIdx.x & 63;
    const int wid  = threadIdx.x >> 6;
    const int ql = lane & 15;
    const int g  = lane >> 4;
    const int rowbase = blockIdx.x * 64 + wid * 16;   // 16 rows per wave
    const int b = rowbase >> 11;

    // A-fragments: row (rowbase+ql), k = 8g..8g+7 (af0) and +32 (af1)
    const float* fr = F + (size_t)(rowbase + ql) * 64;
    union { f32x4 v[2]; float s[8]; } fa0, fa1;
    fa0.v[0] = *(const f32x4*)(fr + 8 * g);
    fa0.v[1] = *(const f32x4*)(fr + 8 * g + 4);
    fa1.v[0] = *(const f32x4*)(fr + 32 + 8 * g);
    fa1.v[1] = *(const f32x4*)(fr + 32 + 8 * g + 4);
    half8 af0, af1;
#pragma unroll
    for (int j = 0; j < 8; ++j) {
        af0[j] = (_Float16)fa0.s[j];
        af1[j] = (_Float16)fa1.s[j];
    }

    const half8* wq = (const half8*)(Wp);
    const half8* wk = (const half8*)(Wp + 4096);
    const half8* wv = (const half8*)(Wp + 8192);

    f32x4 accQ[4], accK[4], accV[4];
#pragma unroll
    for (int dt = 0; dt < 4; ++dt) {
        const int fi = (dt * 16 + ql) * 8;   // half8 index of Wp row d
        f32x4 z = {0.f, 0.f, 0.f, 0.f};
        accQ[dt] = MFMA16(af0, wq[fi + g], z);
        accQ[dt] = MFMA16(af1, wq[fi + 4 + g], accQ[dt]);
        accK[dt] = MFMA16(af0, wk[fi + g], z);
        accK[dt] = MFMA16(af1, wk[fi + 4 + g], accK[dt]);
        accV[dt] = MFMA16(af0, wv[fi + g], z);
        accV[dt] = MFMA16(af1, wv[fi + 4 + g], accV[dt]);
    }

#pragma unroll
    for (int dt = 0; dt < 4; ++dt)
#pragma unroll
        for (int r = 0; r < 4; ++r) {
            const int trow = rowbase + 4 * g + r;
            const int d    = dt * 16 + ql;
            Qh[(size_t)trow * 64 + d] = (_Float16)accQ[dt][r];
            Kh[(size_t)trow * 64 + d] = (_Float16)accK[dt][r];
            Vt[((size_t)b * 64 + d) * T_ + (trow & (T_ - 1))] = (_Float16)accV[dt][r];
        }
}

// pack two fp32 -> fp16x2 in a u32
__device__ inline unsigned pkh(float a, float b)
{
    union { _Float16 h[2]; unsigned u; } z;
    z.h[0] = (_Float16)a;
    z.h[1] = (_Float16)b;
    return z.u;
}

// ---------------------------------------------------------------------------
// Kernel 2: flash attention with intra-block key-split for occupancy.
// Grid = 256 blocks x 16 waves. Block owns 64 q-rows; wave (qt = wid&3,
// ks = wid>>2) computes a flash partial (O, m, l) for q-tile qt over keys
// [512*ks, 512*ks+512). Partials merged through LDS (padded stride 68 ->
// 16B-aligned b128 reads, 2-way bank conflicts only). 16 waves/CU = 4/SIMD.
// ---------------------------------------------------------------------------
__global__ __launch_bounds__(1024) void attn_kernel(
    const _Float16* __restrict__ Qh, const _Float16* __restrict__ Kh,
    const _Float16* __restrict__ Vt, const float* __restrict__ F,
    float* __restrict__ out)
{
    __shared__ float Ol[16][16][68];   // [wave][q][d], pad 68 for align+banks
    __shared__ float Ml[16][16];
    __shared__ float Ll[16][16];

    const int lane = threadIdx.x & 63;
    const int wid  = threadIdx.x >> 6;           // 0..15
    const int qt   = wid & 3;
    const int ks   = wid >> 2;
    const int blk  = blockIdx.x;                 // 0..255
    const int b    = blk >> 5;
    const int qbase = ((blk & 31) << 6) + (qt << 4);  // q offset within batch
    const int ql = lane & 15;
    const int g  = lane >> 4;

    const _Float16* Qbb = Qh + (size_t)b * T_ * 64;
    const _Float16* Kbb = Kh + (size_t)b * T_ * 64;
    const _Float16* Vtb = Vt + (size_t)b * 64 * T_;

    const half8* qp = (const half8*)(Qbb + (qbase + ql) * 64);
    const half8 qf0 = qp[g];
    const half8 qf1 = qp[4 + g];

    f32x4 acc[4];
#pragma unroll
    for (int dt = 0; dt < 4; ++dt) acc[dt] = f32x4{0.f, 0.f, 0.f, 0.f};
    float m    = -1e30f;
    float lsum = 0.f;

    const int L0 = ql | (((2 * g) & 3) << 4);
    const int L1 = ql | (((2 * g + 1) & 3) << 4);
    const bool hi = (g >= 2);
    const int R0 = (lane & 48) | (4 * g + 0);
    const int R1 = (lane & 48) | (4 * g + 1);
    const int R2 = (lane & 48) | (4 * g + 2);
    const int R3 = (lane & 48) | (4 * g + 3);

    const int kb0 = ks << 9;           // 512 keys per split
    for (int kb = kb0; kb < kb0 + 512; kb += 32) {
        const half8* kp0 = (const half8*)(Kbb + (kb + ql) * 64);
        const half8* kp1 = (const half8*)(Kbb + (kb + 16 + ql) * 64);
        // V loads issued early so they are in flight during softmax
        const half8 v0 = *(const half8*)(Vtb + (0 * 16 + ql) * T_ + kb + g * 8);
        const half8 v1 = *(const half8*)(Vtb + (1 * 16 + ql) * T_ + kb + g * 8);
        const half8 v2 = *(const half8*)(Vtb + (2 * 16 + ql) * T_ + kb + g * 8);
        const half8 v3 = *(const half8*)(Vtb + (3 * 16 + ql) * T_ + kb + g * 8);

        f32x4 s0 = {0.f, 0.f, 0.f, 0.f};
        f32x4 s1 = {0.f, 0.f, 0.f, 0.f};
        s0 = MFMA16(kp0[g], qf0, s0);
        s0 = MFMA16(kp0[4 + g], qf1, s0);
        s1 = MFMA16(kp1[g], qf0, s1);
        s1 = MFMA16(kp1[4 + g], qf1, s1);

        float p0 = s0[0] * LOG2E, p1 = s0[1] * LOG2E;
        float p2 = s0[2] * LOG2E, p3 = s0[3] * LOG2E;
        float p4 = s1[0] * LOG2E, p5 = s1[1] * LOG2E;
        float p6 = s1[2] * LOG2E, p7 = s1[3] * LOG2E;

        float pm = fmaxf(fmaxf(fmaxf(p0, p1), fmaxf(p2, p3)),
                         fmaxf(fmaxf(p4, p5), fmaxf(p6, p7)));
        pm = fmaxf(pm, __shfl_xor(pm, 16));
        pm = fmaxf(pm, __shfl_xor(pm, 32));
        const float mnew = fmaxf(m, pm);
        const float fac  = exp2f(m - mnew);
        m = mnew;

        p0 = exp2f(p0 - mnew); p1 = exp2f(p1 - mnew);
        p2 = exp2f(p2 - mnew); p3 = exp2f(p3 - mnew);
        p4 = exp2f(p4 - mnew); p5 = exp2f(p5 - mnew);
        p6 = exp2f(p6 - mnew); p7 = exp2f(p7 - mnew);

        float psum = ((p0 + p1) + (p2 + p3)) + ((p4 + p5) + (p6 + p7));
        psum += __shfl_xor(psum, 16);
        psum += __shfl_xor(psum, 32);
        lsum = lsum * fac + psum;

        const unsigned t0a = pkh(p0, p1), t0b = pkh(p2, p3);
        const unsigned t1a = pkh(p4, p5), t1b = pkh(p6, p7);
        const unsigned x0a = (unsigned)__shfl((int)t0a, L0);
        const unsigned x1a = (unsigned)__shfl((int)t1a, L0);
        const unsigned x0b = (unsigned)__shfl((int)t0b, L0);
        const unsigned x1b = (unsigned)__shfl((int)t1b, L0);
        const unsigned y0a = (unsigned)__shfl((int)t0a, L1);
        const unsigned y1a = (unsigned)__shfl((int)t1a, L1);
        const unsigned y0b = (unsigned)__shfl((int)t0b, L1);
        const unsigned y1b = (unsigned)__shfl((int)t1b, L1);
        union { unsigned u[4]; half8 v; } pa;
        pa.u[0] = hi ? x1a : x0a;
        pa.u[1] = hi ? x1b : x0b;
        pa.u[2] = hi ? y1a : y0a;
        pa.u[3] = hi ? y1b : y0b;

        const float f0 = __shfl(fac, R0);
        const float f1 = __shfl(fac, R1);
        const float f2 = __shfl(fac, R2);
        const float f3 = __shfl(fac, R3);
#pragma unroll
        for (int dt = 0; dt < 4; ++dt) {
            acc[dt][0] *= f0; acc[dt][1] *= f1;
            acc[dt][2] *= f2; acc[dt][3] *= f3;
        }

        acc[0] = MFMA16(pa.v, v0, acc[0]);
        acc[1] = MFMA16(pa.v, v1, acc[1]);
        acc[2] = MFMA16(pa.v, v2, acc[2]);
        acc[3] = MFMA16(pa.v, v3, acc[3]);
    }

    // ---- write partials to LDS ----
#pragma unroll
    for (int dt = 0; dt < 4; ++dt)
#pragma unroll
        for (int r = 0; r < 4; ++r)
            Ol[wid][4 * g + r][dt * 16 + ql] = acc[dt][r];
    if (g == 0) {
        Ml[wid][ql] = m;
        Ll[wid][ql] = lsum;
    }
    __syncthreads();

    // ---- combine 4 key-splits; each wave finishes 4 q-rows ----
    const int qq  = 4 * wid + (lane >> 4);       // row within block [0,64)
    const int qt2 = qq >> 4;
    const int qr  = qq & 15;
    const int d0  = (lane & 15) * 4;

    float mm[4], lv[4];
#pragma unroll
    for (int s = 0; s < 4; ++s) {
        mm[s] = Ml[qt2 + 4 * s][qr];
        lv[s] = Ll[qt2 + 4 * s][qr];
    }
    const float ms = fmaxf(fmaxf(mm[0], mm[1]), fmaxf(mm[2], mm[3]));
    float lt = 0.f;
    f32x4 o = {0.f, 0.f, 0.f, 0.f};
#pragma unroll
    for (int s = 0; s < 4; ++s) {
        const float sc = exp2f(mm[s] - ms);
        lt += lv[s] * sc;
        const f32x4 ov = *(const f32x4*)(&Ol[qt2 + 4 * s][qr][d0]);
        o += ov * sc;
    }
    const float inv = 1.0f / lt;
    const size_t grow = (size_t)b * T_ + ((blk & 31) << 6) + qq;
    const f32x4 fres = *(const f32x4*)(F + grow * 64 + d0);
    f32x4 res = o * inv + fres;
    *(f32x4*)(out + grow * 64 + d0) = res;
}

extern "C" void kernel_launch(void* const* d_in, const int* in_sizes, int n_in,
                              void* d_out, int out_size, void* d_ws, size_t ws_size,
                              hipStream_t stream)
{
    const float* F  = (const float*)d_in[0];
    const float* WM = (const float*)d_in[1];
    const float* WN = (const float*)d_in[2];
    const float* WV = (const float*)d_in[3];
    float* out = (float*)d_out;

    const size_t proj_bytes = (size_t)B_ * T_ * 64 * sizeof(_Float16); // 2 MB
    char* ws = (char*)d_ws;
    _Float16* Qh = (_Float16*)(ws);
    _Float16* Kh = (_Float16*)(ws + proj_bytes);
    _Float16* Vt = (_Float16*)(ws + 2 * proj_bytes);
    _Float16* Wp = (_Float16*)(ws + 3 * proj_bytes);  // 3*64*64 f16 = 24 KB

    hipLaunchKernelGGL(prepack_kernel, dim3(1), dim3(256), 0, stream,
                       WM, WN, WV, Wp);
    hipLaunchKernelGGL(proj_kernel, dim3(B_ * T_ / 64), dim3(256), 0, stream,
                       F, Wp, Qh, Kh, Vt);
    hipLaunchKernelGGL(attn_kernel, dim3(B_ * T_ / 64), dim3(1024), 0, stream,
                       Qh, Kh, Vt, F, out);
}

// Round 4
// 77.626 us; speedup vs baseline: 1.3012x; 1.0224x over previous
//
#include <hip/hip_runtime.h>
#include <hip/hip_bf16.h>

// Problem constants (fixed by reference): B=8, T=2048, C=64
#define B_ 8
#define T_ 2048
#define LOG2E 1.4426950408889634f

typedef _Float16 half8 __attribute__((ext_vector_type(8)));
typedef float f32x4 __attribute__((ext_vector_type(4)));

#define MFMA16(A, Bv, Cv) __builtin_amdgcn_mfma_f32_16x16x32_f16((A), (Bv), (Cv), 0, 0, 0)

// ---------------------------------------------------------------------------
// Kernel 0: pre-pack weights. W [k][d] fp32 -> Wp [mat][d][k] f16.
// 48 blocks x 256 threads, one element each (12288 total).
// ---------------------------------------------------------------------------
__global__ __launch_bounds__(256) void prepack_kernel(
    const float* __restrict__ WM, const float* __restrict__ WN,
    const float* __restrict__ WV, _Float16* __restrict__ Wp)
{
    const int idx = blockIdx.x * 256 + threadIdx.x;   // [0, 12288)
    const int m = idx >> 12;
    const int r = idx & 4095;
    const int d = r >> 6;
    const int k = r & 63;
    const float* W = (m == 0) ? WM : (m == 1) ? WN : WV;
    Wp[m * 4096 + d * 64 + k] = (_Float16)W[k * 64 + d];
}

// ---------------------------------------------------------------------------
// Kernel 1: MFMA projections. Each wave: 16 rows x 64 cols, 24 mfma.
// Q is pre-scaled by LOG2E (scores land directly in base-2 domain).
// Q,K row-major f16; V transposed Vt[b][d][t] f16.
// ---------------------------------------------------------------------------
__global__ __launch_bounds__(256) void proj_kernel(
    const float* __restrict__ F, const _Float16* __restrict__ Wp,
    _Float16* __restrict__ Qh, _Float16* __restrict__ Kh,
    _Float16* __restrict__ Vt)
{
    const int lane = threadIdx.x & 63;
    const int wid  = threadIdx.x >> 6;
    const int ql = lane & 15;
    const int g  = lane >> 4;
    const int rowbase = blockIdx.x * 64 + wid * 16;
    const int b = rowbase >> 11;

    const float* fr = F + (size_t)(rowbase + ql) * 64;
    union { f32x4 v[2]; float s[8]; } fa0, fa1;
    fa0.v[0] = *(const f32x4*)(fr + 8 * g);
    fa0.v[1] = *(const f32x4*)(fr + 8 * g + 4);
    fa1.v[0] = *(const f32x4*)(fr + 32 + 8 * g);
    fa1.v[1] = *(const f32x4*)(fr + 32 + 8 * g + 4);
    half8 af0, af1;
#pragma unroll
    for (int j = 0; j < 8; ++j) {
        af0[j] = (_Float16)fa0.s[j];
        af1[j] = (_Float16)fa1.s[j];
    }

    const half8* wq = (const half8*)(Wp);
    const half8* wk = (const half8*)(Wp + 4096);
    const half8* wv = (const half8*)(Wp + 8192);

    f32x4 accQ[4], accK[4], accV[4];
#pragma unroll
    for (int dt = 0; dt < 4; ++dt) {
        const int fi = (dt * 16 + ql) * 8;
        f32x4 z = {0.f, 0.f, 0.f, 0.f};
        accQ[dt] = MFMA16(af0, wq[fi + g], z);
        accQ[dt] = MFMA16(af1, wq[fi + 4 + g], accQ[dt]);
        accK[dt] = MFMA16(af0, wk[fi + g], z);
        accK[dt] = MFMA16(af1, wk[fi + 4 + g], accK[dt]);
        accV[dt] = MFMA16(af0, wv[fi + g], z);
        accV[dt] = MFMA16(af1, wv[fi + 4 + g], accV[dt]);
    }

#pragma unroll
    for (int dt = 0; dt < 4; ++dt)
#pragma unroll
        for (int r = 0; r < 4; ++r) {
            const int trow = rowbase + 4 * g + r;
            const int d    = dt * 16 + ql;
            Qh[(size_t)trow * 64 + d] = (_Float16)(accQ[dt][r] * LOG2E);
            Kh[(size_t)trow * 64 + d] = (_Float16)accK[dt][r];
            Vt[((size_t)b * 64 + d) * T_ + (trow & (T_ - 1))] = (_Float16)accV[dt][r];
        }
}

// pack two fp32 -> fp16x2 in a u32
__device__ inline unsigned pkh(float a, float b)
{
    union { _Float16 h[2]; unsigned u; } z;
    z.h[0] = (_Float16)a;
    z.h[1] = (_Float16)b;
    return z.u;
}

// ---------------------------------------------------------------------------
// Kernel 2: flash attention, batch-per-XCD affinity.
// Grid = 256 blocks x 16 waves. b = blockIdx&7: blocks round-robin XCDs, so
// batch b's K/V/Q/F (~1.3 MB) stays resident in one XCD's 4 MB L2 instead of
// all 8 batches thrashing every L2 (R2's 2x over-fetch, 64 us plateau).
// Wave (qt, ks) computes a flash partial over 512 keys; merged in LDS.
// Softmax: verified __shfl_xor reductions; defer-max (T13, THR=8 base-2).
// ---------------------------------------------------------------------------
__global__ __launch_bounds__(1024) void attn_kernel(
    const _Float16* __restrict__ Qh, const _Float16* __restrict__ Kh,
    const _Float16* __restrict__ Vt, const float* __restrict__ F,
    float* __restrict__ out)
{
    __shared__ float Ol[16][16][68];
    __shared__ float Ml[16][16];
    __shared__ float Ll[16][16];

    const int lane = threadIdx.x & 63;
    const int wid  = threadIdx.x >> 6;           // 0..15
    const int qt   = wid & 3;
    const int ks   = wid >> 2;
    const int blk  = blockIdx.x;                 // 0..255
    const int b    = blk & 7;                    // XCD-affine batch
    const int tile = blk >> 3;                   // 0..31
    const int qbase = (tile << 6) + (qt << 4);
    const int ql = lane & 15;
    const int g  = lane >> 4;

    const _Float16* Qbb = Qh + (size_t)b * T_ * 64;
    const _Float16* Kbb = Kh + (size_t)b * T_ * 64;
    const _Float16* Vtb = Vt + (size_t)b * 64 * T_;

    const half8* qp = (const half8*)(Qbb + (qbase + ql) * 64);
    const half8 qf0 = qp[g];
    const half8 qf1 = qp[4 + g];

    f32x4 acc[4];
#pragma unroll
    for (int dt = 0; dt < 4; ++dt) acc[dt] = f32x4{0.f, 0.f, 0.f, 0.f};
    float m    = -1e30f;
    float lsum = 0.f;

    const int L0 = ql | (((2 * g) & 3) << 4);
    const int L1 = ql | (((2 * g + 1) & 3) << 4);
    const bool hi = (g >= 2);
    const int R0 = (lane & 48) | (4 * g + 0);
    const int R1 = (lane & 48) | (4 * g + 1);
    const int R2 = (lane & 48) | (4 * g + 2);
    const int R3 = (lane & 48) | (4 * g + 3);

    const int kb0 = ks << 9;
    for (int kb = kb0; kb < kb0 + 512; kb += 32) {
        const half8* kp0 = (const half8*)(Kbb + (kb + ql) * 64);
        const half8* kp1 = (const half8*)(Kbb + (kb + 16 + ql) * 64);
        const half8 v0 = *(const half8*)(Vtb + (0 * 16 + ql) * T_ + kb + g * 8);
        const half8 v1 = *(const half8*)(Vtb + (1 * 16 + ql) * T_ + kb + g * 8);
        const half8 v2 = *(const half8*)(Vtb + (2 * 16 + ql) * T_ + kb + g * 8);
        const half8 v3 = *(const half8*)(Vtb + (3 * 16 + ql) * T_ + kb + g * 8);

        f32x4 s0 = {0.f, 0.f, 0.f, 0.f};
        f32x4 s1 = {0.f, 0.f, 0.f, 0.f};
        s0 = MFMA16(kp0[g], qf0, s0);
        s0 = MFMA16(kp0[4 + g], qf1, s0);
        s1 = MFMA16(kp1[g], qf0, s1);
        s1 = MFMA16(kp1[4 + g], qf1, s1);

        // scores already in base-2 (Q pre-scaled by LOG2E)
        float p0 = s0[0], p1 = s0[1], p2 = s0[2], p3 = s0[3];
        float p4 = s1[0], p5 = s1[1], p6 = s1[2], p7 = s1[3];

        float pm = fmaxf(fmaxf(fmaxf(p0, p1), fmaxf(p2, p3)),
                         fmaxf(fmaxf(p4, p5), fmaxf(p6, p7)));
        pm = fmaxf(pm, __shfl_xor(pm, 16));
        pm = fmaxf(pm, __shfl_xor(pm, 32));

        float fac = 1.0f;
        if (__any(pm - m > 8.0f)) {              // defer-max (T13)
            const float mnew = fmaxf(m, pm);
            fac = exp2f(m - mnew);
            m = mnew;
            const float f0 = __shfl(fac, R0);
            const float f1 = __shfl(fac, R1);
            const float f2 = __shfl(fac, R2);
            const float f3 = __shfl(fac, R3);
#pragma unroll
            for (int dt = 0; dt < 4; ++dt) {
                acc[dt][0] *= f0; acc[dt][1] *= f1;
                acc[dt][2] *= f2; acc[dt][3] *= f3;
            }
        }

        p0 = exp2f(p0 - m); p1 = exp2f(p1 - m);
        p2 = exp2f(p2 - m); p3 = exp2f(p3 - m);
        p4 = exp2f(p4 - m); p5 = exp2f(p5 - m);
        p6 = exp2f(p6 - m); p7 = exp2f(p7 - m);

        float psum = ((p0 + p1) + (p2 + p3)) + ((p4 + p5) + (p6 + p7));
        psum += __shfl_xor(psum, 16);
        psum += __shfl_xor(psum, 32);
        lsum = lsum * fac + psum;

        // ---- pack P to f16 and regroup into PV A-fragment (R2-verified) ----
        const unsigned t0a = pkh(p0, p1), t0b = pkh(p2, p3);
        const unsigned t1a = pkh(p4, p5), t1b = pkh(p6, p7);
        const unsigned x0a = (unsigned)__shfl((int)t0a, L0);
        const unsigned x1a = (unsigned)__shfl((int)t1a, L0);
        const unsigned x0b = (unsigned)__shfl((int)t0b, L0);
        const unsigned x1b = (unsigned)__shfl((int)t1b, L0);
        const unsigned y0a = (unsigned)__shfl((int)t0a, L1);
        const unsigned y1a = (unsigned)__shfl((int)t1a, L1);
        const unsigned y0b = (unsigned)__shfl((int)t0b, L1);
        const unsigned y1b = (unsigned)__shfl((int)t1b, L1);
        union { unsigned u[4]; half8 v; } pa;
        pa.u[0] = hi ? x1a : x0a;
        pa.u[1] = hi ? x1b : x0b;
        pa.u[2] = hi ? y1a : y0a;
        pa.u[3] = hi ? y1b : y0b;

        acc[0] = MFMA16(pa.v, v0, acc[0]);
        acc[1] = MFMA16(pa.v, v1, acc[1]);
        acc[2] = MFMA16(pa.v, v2, acc[2]);
        acc[3] = MFMA16(pa.v, v3, acc[3]);
    }

    // ---- write partials to LDS ----
#pragma unroll
    for (int dt = 0; dt < 4; ++dt)
#pragma unroll
        for (int r = 0; r < 4; ++r)
            Ol[wid][4 * g + r][dt * 16 + ql] = acc[dt][r];
    if (g == 0) {
        Ml[wid][ql] = m;
        Ll[wid][ql] = lsum;
    }
    __syncthreads();

    // ---- combine 4 key-splits; each wave finishes 4 q-rows ----
    const int qq  = 4 * wid + (lane >> 4);
    const int qt2 = qq >> 4;
    const int qr  = qq & 15;
    const int d0  = (lane & 15) * 4;

    float mm[4], lv[4];
#pragma unroll
    for (int s = 0; s < 4; ++s) {
        mm[s] = Ml[qt2 + 4 * s][qr];
        lv[s] = Ll[qt2 + 4 * s][qr];
    }
    const float ms = fmaxf(fmaxf(mm[0], mm[1]), fmaxf(mm[2], mm[3]));
    float lt = 0.f;
    f32x4 o = {0.f, 0.f, 0.f, 0.f};
#pragma unroll
    for (int s = 0; s < 4; ++s) {
        const float sc = exp2f(mm[s] - ms);
        lt += lv[s] * sc;
        const f32x4 ov = *(const f32x4*)(&Ol[qt2 + 4 * s][qr][d0]);
        o += ov * sc;
    }
    const float inv = 1.0f / lt;
    const size_t grow = (size_t)b * T_ + (tile << 6) + qq;
    const f32x4 fres = *(const f32x4*)(F + grow * 64 + d0);
    f32x4 res = o * inv + fres;
    *(f32x4*)(out + grow * 64 + d0) = res;
}

extern "C" void kernel_launch(void* const* d_in, const int* in_sizes, int n_in,
                              void* d_out, int out_size, void* d_ws, size_t ws_size,
                              hipStream_t stream)
{
    const float* F  = (const float*)d_in[0];
    const float* WM = (const float*)d_in[1];
    const float* WN = (const float*)d_in[2];
    const float* WV = (const float*)d_in[3];
    float* out = (float*)d_out;

    const size_t proj_bytes = (size_t)B_ * T_ * 64 * sizeof(_Float16); // 2 MB
    char* ws = (char*)d_ws;
    _Float16* Qh = (_Float16*)(ws);
    _Float16* Kh = (_Float16*)(ws + proj_bytes);
    _Float16* Vt = (_Float16*)(ws + 2 * proj_bytes);
    _Float16* Wp = (_Float16*)(ws + 3 * proj_bytes);  // 3*64*64 f16 = 24 KB

    hipLaunchKernelGGL(prepack_kernel, dim3(48), dim3(256), 0, stream,
                       WM, WN, WV, Wp);
    hipLaunchKernelGGL(proj_kernel, dim3(B_ * T_ / 64), dim3(256), 0, stream,
                       F, Wp, Qh, Kh, Vt);
    hipLaunchKernelGGL(attn_kernel, dim3(B_ * T_ / 64), dim3(1024), 0, stream,
                       Qh, Kh, Vt, F, out);
}

// Round 6
// 42.887 us; speedup vs baseline: 2.3551x; 1.8100x over previous
//
#include <hip/hip_runtime.h>
#include <hip/hip_bf16.h>

// Problem constants (fixed by reference): B=8, T=2048, C=64
#define B_ 8
#define T_ 2048
#define LOG2E 1.4426950408889634f

typedef _Float16 half8 __attribute__((ext_vector_type(8)));
typedef float f32x4 __attribute__((ext_vector_type(4)));

#define MFMA16(A, Bv, Cv) __builtin_amdgcn_mfma_f32_16x16x32_f16((A), (Bv), (Cv), 0, 0, 0)

// ---------------------------------------------------------------------------
// Kernel 0: pre-pack weights. W [k][d] fp32 -> Wp [mat][d][k] f16.
// ---------------------------------------------------------------------------
__global__ __launch_bounds__(256) void prepack_kernel(
    const float* __restrict__ WM, const float* __restrict__ WN,
    const float* __restrict__ WV, _Float16* __restrict__ Wp)
{
    const int idx = blockIdx.x * 256 + threadIdx.x;   // [0, 12288)
    const int m = idx >> 12;
    const int r = idx & 4095;
    const int d = r >> 6;
    const int k = r & 63;
    const float* W = (m == 0) ? WM : (m == 1) ? WN : WV;
    Wp[m * 4096 + d * 64 + k] = (_Float16)W[k * 64 + d];
}

// ---------------------------------------------------------------------------
// Kernel 1: MFMA projections -> fragment-major K/V layouts.
// Q: row-major f16, pre-scaled by LOG2E.
// Kf: per-batch 16-key tiles: [kt][p=((d>>5)<<2)|((d>>3)&3)][t&15][d&7]
//     tile = 8*16 = 128 half8; attn K-fragment load is 64 lanes x 16B = 1KB
//     fully contiguous.
// Vf: per-batch 32-key tiles: [kt5][dt=d>>4][d&15][(t&31)>>3][t&7]
//     tile = 4*16*4 = 256 half8; attn V-fragment load likewise 1KB contiguous.
// ---------------------------------------------------------------------------
__global__ __launch_bounds__(256) void proj_kernel(
    const float* __restrict__ F, const _Float16* __restrict__ Wp,
    _Float16* __restrict__ Qh, _Float16* __restrict__ Kf,
    _Float16* __restrict__ Vf)
{
    const int lane = threadIdx.x & 63;
    const int wid  = threadIdx.x >> 6;
    const int ql = lane & 15;
    const int g  = lane >> 4;
    const int rowbase = blockIdx.x * 64 + wid * 16;
    const int b = rowbase >> 11;

    const float* fr = F + (size_t)(rowbase + ql) * 64;
    union { f32x4 v[2]; float s[8]; } fa0, fa1;
    fa0.v[0] = *(const f32x4*)(fr + 8 * g);
    fa0.v[1] = *(const f32x4*)(fr + 8 * g + 4);
    fa1.v[0] = *(const f32x4*)(fr + 32 + 8 * g);
    fa1.v[1] = *(const f32x4*)(fr + 32 + 8 * g + 4);
    half8 af0, af1;
#pragma unroll
    for (int j = 0; j < 8; ++j) {
        af0[j] = (_Float16)fa0.s[j];
        af1[j] = (_Float16)fa1.s[j];
    }

    const half8* wq = (const half8*)(Wp);
    const half8* wk = (const half8*)(Wp + 4096);
    const half8* wv = (const half8*)(Wp + 8192);

    f32x4 accQ[4], accK[4], accV[4];
#pragma unroll
    for (int dt = 0; dt < 4; ++dt) {
        const int fi = (dt * 16 + ql) * 8;
        f32x4 z = {0.f, 0.f, 0.f, 0.f};
        accQ[dt] = MFMA16(af0, wq[fi + g], z);
        accQ[dt] = MFMA16(af1, wq[fi + 4 + g], accQ[dt]);
        accK[dt] = MFMA16(af0, wk[fi + g], z);
        accK[dt] = MFMA16(af1, wk[fi + 4 + g], accK[dt]);
        accV[dt] = MFMA16(af0, wv[fi + g], z);
        accV[dt] = MFMA16(af1, wv[fi + 4 + g], accV[dt]);
    }

#pragma unroll
    for (int dt = 0; dt < 4; ++dt)
#pragma unroll
        for (int r = 0; r < 4; ++r) {
            const int trow = rowbase + 4 * g + r;
            const int tt   = trow & (T_ - 1);
            const int d    = dt * 16 + ql;
            Qh[(size_t)trow * 64 + d] = (_Float16)(accQ[dt][r] * LOG2E);
            // K fragment-major
            {
                const int kt = tt >> 4, qr = tt & 15;
                const int p  = ((d >> 5) << 2) | ((d >> 3) & 3);
                Kf[(((size_t)b * 128 + kt) * 8 + p) * 128 + qr * 8 + (d & 7)]
                    = (_Float16)accK[dt][r];
            }
            // V fragment-major
            {
                const int kt5 = tt >> 5, c = tt & 31;
                Vf[(((((size_t)b * 64 + kt5) * 4 + dt) * 16 + ql) * 4 + (c >> 3)) * 8 + (c & 7)]
                    = (_Float16)accV[dt][r];
            }
        }
}

// pack two fp32 -> fp16x2 in a u32
__device__ inline unsigned pkh(float a, float b)
{
    union { _Float16 h[2]; unsigned u; } z;
    z.h[0] = (_Float16)a;
    z.h[1] = (_Float16)b;
    return z.u;
}

struct QTile {
    half8 qf0, qf1;
    f32x4 acc[4];
    float m, lsum;
};

// One q-tile's QK^T -> online softmax -> PV for a 32-key chunk.
// All lane machinery identical to the R2/R4-verified kernel.
__device__ __forceinline__ void process_tile(
    QTile& t,
    const half8 k0lo, const half8 k0hi, const half8 k1lo, const half8 k1hi,
    const half8 v0, const half8 v1, const half8 v2, const half8 v3,
    const int L0, const int L1, const bool hi,
    const int R0, const int R1, const int R2, const int R3)
{
    f32x4 s0 = {0.f, 0.f, 0.f, 0.f};
    f32x4 s1 = {0.f, 0.f, 0.f, 0.f};
    s0 = MFMA16(k0lo, t.qf0, s0);
    s0 = MFMA16(k0hi, t.qf1, s0);
    s1 = MFMA16(k1lo, t.qf0, s1);
    s1 = MFMA16(k1hi, t.qf1, s1);

    float p0 = s0[0], p1 = s0[1], p2 = s0[2], p3 = s0[3];
    float p4 = s1[0], p5 = s1[1], p6 = s1[2], p7 = s1[3];

    float pm = fmaxf(fmaxf(fmaxf(p0, p1), fmaxf(p2, p3)),
                     fmaxf(fmaxf(p4, p5), fmaxf(p6, p7)));
    pm = fmaxf(pm, __shfl_xor(pm, 16));
    pm = fmaxf(pm, __shfl_xor(pm, 32));

    float fac = 1.0f;
    if (__any(pm - t.m > 8.0f)) {              // defer-max (T13)
        const float mnew = fmaxf(t.m, pm);
        fac = exp2f(t.m - mnew);
        t.m = mnew;
        const float f0 = __shfl(fac, R0);
        const float f1 = __shfl(fac, R1);
        const float f2 = __shfl(fac, R2);
        const float f3 = __shfl(fac, R3);
#pragma unroll
        for (int dt = 0; dt < 4; ++dt) {
            t.acc[dt][0] *= f0; t.acc[dt][1] *= f1;
            t.acc[dt][2] *= f2; t.acc[dt][3] *= f3;
        }
    }

    p0 = exp2f(p0 - t.m); p1 = exp2f(p1 - t.m);
    p2 = exp2f(p2 - t.m); p3 = exp2f(p3 - t.m);
    p4 = exp2f(p4 - t.m); p5 = exp2f(p5 - t.m);
    p6 = exp2f(p6 - t.m); p7 = exp2f(p7 - t.m);

    float psum = ((p0 + p1) + (p2 + p3)) + ((p4 + p5) + (p6 + p7));
    psum += __shfl_xor(psum, 16);
    psum += __shfl_xor(psum, 32);
    t.lsum = t.lsum * fac + psum;

    const unsigned t0a = pkh(p0, p1), t0b = pkh(p2, p3);
    const unsigned t1a = pkh(p4, p5), t1b = pkh(p6, p7);
    const unsigned x0a = (unsigned)__shfl((int)t0a, L0);
    const unsigned x1a = (unsigned)__shfl((int)t1a, L0);
    const unsigned x0b = (unsigned)__shfl((int)t0b, L0);
    const unsigned x1b = (unsigned)__shfl((int)t1b, L0);
    const unsigned y0a = (unsigned)__shfl((int)t0a, L1);
    const unsigned y1a = (unsigned)__shfl((int)t1a, L1);
    const unsigned y0b = (unsigned)__shfl((int)t0b, L1);
    const unsigned y1b = (unsigned)__shfl((int)t1b, L1);
    union { unsigned u[4]; half8 v; } pa;
    pa.u[0] = hi ? x1a : x0a;
    pa.u[1] = hi ? x1b : x0b;
    pa.u[2] = hi ? y1a : y0a;
    pa.u[3] = hi ? y1b : y0b;

    t.acc[0] = MFMA16(pa.v, v0, t.acc[0]);
    t.acc[1] = MFMA16(pa.v, v1, t.acc[1]);
    t.acc[2] = MFMA16(pa.v, v2, t.acc[2]);
    t.acc[3] = MFMA16(pa.v, v3, t.acc[3]);
}

// ---------------------------------------------------------------------------
// Kernel 2: flash attention. Grid = 256 blocks x 8 waves (512 thr).
// b = blk&7 (XCD affinity), block owns 64 q-rows. Wave (qt=wid&1, ks=wid>>1)
// processes TWO 16-row q-tiles (rows qt*32..qt*32+31) over keys
// [512*ks, 512*ks+512): 8 fully-coalesced 1KB loads serve 16 MFMA per iter
// (2x work per VMEM segment vs R4). Partials merged in LDS.
// ---------------------------------------------------------------------------
__global__ __launch_bounds__(512) void attn_kernel(
    const _Float16* __restrict__ Qh, const _Float16* __restrict__ Kf,
    const _Float16* __restrict__ Vf, const float* __restrict__ F,
    float* __restrict__ out)
{
    __shared__ float Ol[8][32][68];
    __shared__ float Ml[8][32];
    __shared__ float Ll[8][32];

    const int lane = threadIdx.x & 63;
    const int wid  = threadIdx.x >> 6;           // 0..7
    const int qt   = wid & 1;
    const int ks   = wid >> 1;                   // 0..3
    const int blk  = blockIdx.x;                 // 0..255
    const int b    = blk & 7;                    // XCD-affine batch
    const int tile = blk >> 3;                   // 0..31
    const int ql = lane & 15;
    const int g  = lane >> 4;

    const _Float16* Qbb = Qh + (size_t)b * T_ * 64;
    const half8* KfB = (const half8*)Kf + (size_t)b * 16384;  // 128 tiles * 128
    const half8* VfB = (const half8*)Vf + (size_t)b * 16384;  // 64 tiles * 256

    QTile tA, tB;
    {
        const int qbaseA = (tile << 6) + qt * 32;
        const half8* qpA = (const half8*)(Qbb + (qbaseA + ql) * 64);
        const half8* qpB = (const half8*)(Qbb + (qbaseA + 16 + ql) * 64);
        tA.qf0 = qpA[g];  tA.qf1 = qpA[4 + g];
        tB.qf0 = qpB[g];  tB.qf1 = qpB[4 + g];
    }
#pragma unroll
    for (int dt = 0; dt < 4; ++dt) {
        tA.acc[dt] = f32x4{0.f, 0.f, 0.f, 0.f};
        tB.acc[dt] = f32x4{0.f, 0.f, 0.f, 0.f};
    }
    tA.m = -1e30f; tA.lsum = 0.f;
    tB.m = -1e30f; tB.lsum = 0.f;

    const int L0 = ql | (((2 * g) & 3) << 4);
    const int L1 = ql | (((2 * g + 1) & 3) << 4);
    const bool hi = (g >= 2);
    const int R0 = (lane & 48) | (4 * g + 0);
    const int R1 = (lane & 48) | (4 * g + 1);
    const int R2 = (lane & 48) | (4 * g + 2);
    const int R3 = (lane & 48) | (4 * g + 3);

    const int kb0 = ks << 9;                     // 512 keys per split
    for (int kb = kb0; kb < kb0 + 512; kb += 32) {
        // K fragments: two 16-key sub-tiles (tile stride 128 half8)
        const half8* ktb = KfB + (size_t)(kb >> 4) * 128;
        const half8 k0lo = ktb[g * 16 + ql];
        const half8 k0hi = ktb[(4 + g) * 16 + ql];
        const half8 k1lo = ktb[128 + g * 16 + ql];
        const half8 k1hi = ktb[128 + (4 + g) * 16 + ql];
        // V fragments: one 32-key tile (tile stride 256 half8 -- R5 bug was 512)
        const half8* vtb = VfB + (size_t)(kb >> 5) * 256;
        const half8 v0 = vtb[(0 * 16 + ql) * 4 + g];
        const half8 v1 = vtb[(1 * 16 + ql) * 4 + g];
        const half8 v2 = vtb[(2 * 16 + ql) * 4 + g];
        const half8 v3 = vtb[(3 * 16 + ql) * 4 + g];

        process_tile(tA, k0lo, k0hi, k1lo, k1hi, v0, v1, v2, v3,
                     L0, L1, hi, R0, R1, R2, R3);
        process_tile(tB, k0lo, k0hi, k1lo, k1hi, v0, v1, v2, v3,
                     L0, L1, hi, R0, R1, R2, R3);
    }

    // ---- write partials to LDS: wave rows 0..15 = tile A, 16..31 = tile B
#pragma unroll
    for (int dt = 0; dt < 4; ++dt)
#pragma unroll
        for (int r = 0; r < 4; ++r) {
            Ol[wid][4 * g + r][dt * 16 + ql]      = tA.acc[dt][r];
            Ol[wid][16 + 4 * g + r][dt * 16 + ql] = tB.acc[dt][r];
        }
    if (g == 0) {
        Ml[wid][ql] = tA.m;       Ll[wid][ql] = tA.lsum;
        Ml[wid][16 + ql] = tB.m;  Ll[wid][16 + ql] = tB.lsum;
    }
    __syncthreads();

    // ---- combine 4 key-splits; 512 threads, one (row, 8-col chunk) each ----
    const int tid  = threadIdx.x;
    const int qq   = tid >> 3;                   // 0..63 row within block
    const int d0   = (tid & 7) * 8;
    const int qt_m = qq >> 5;
    const int lr   = qq & 31;

    float mm[4], lv[4];
#pragma unroll
    for (int s = 0; s < 4; ++s) {
        const int w = qt_m + 2 * s;
        mm[s] = Ml[w][lr];
        lv[s] = Ll[w][lr];
    }
    const float ms = fmaxf(fmaxf(mm[0], mm[1]), fmaxf(mm[2], mm[3]));
    float lt = 0.f;
    f32x4 oa = {0.f, 0.f, 0.f, 0.f};
    f32x4 ob2 = {0.f, 0.f, 0.f, 0.f};
#pragma unroll
    for (int s = 0; s < 4; ++s) {
        const int w = qt_m + 2 * s;
        const float sc = exp2f(mm[s] - ms);
        lt += lv[s] * sc;
        oa  += *(const f32x4*)(&Ol[w][lr][d0])     * sc;
        ob2 += *(const f32x4*)(&Ol[w][lr][d0 + 4]) * sc;
    }
    const float inv = 1.0f / lt;
    const size_t grow = (size_t)b * T_ + (tile << 6) + qq;
    const f32x4 fr0 = *(const f32x4*)(F + grow * 64 + d0);
    const f32x4 fr1 = *(const f32x4*)(F + grow * 64 + d0 + 4);
    *(f32x4*)(out + grow * 64 + d0)     = oa * inv + fr0;
    *(f32x4*)(out + grow * 64 + d0 + 4) = ob2 * inv + fr1;
}

extern "C" void kernel_launch(void* const* d_in, const int* in_sizes, int n_in,
                              void* d_out, int out_size, void* d_ws, size_t ws_size,
                              hipStream_t stream)
{
    const float* F  = (const float*)d_in[0];
    const float* WM = (const float*)d_in[1];
    const float* WN = (const float*)d_in[2];
    const float* WV = (const float*)d_in[3];
    float* out = (float*)d_out;

    const size_t proj_bytes = (size_t)B_ * T_ * 64 * sizeof(_Float16); // 2 MB
    char* ws = (char*)d_ws;
    _Float16* Qh = (_Float16*)(ws);
    _Float16* Kf = (_Float16*)(ws + proj_bytes);
    _Float16* Vf = (_Float16*)(ws + 2 * proj_bytes);
    _Float16* Wp = (_Float16*)(ws + 3 * proj_bytes);  // 3*64*64 f16 = 24 KB

    hipLaunchKernelGGL(prepack_kernel, dim3(48), dim3(256), 0, stream,
                       WM, WN, WV, Wp);
    hipLaunchKernelGGL(proj_kernel, dim3(B_ * T_ / 64), dim3(256), 0, stream,
                       F, Wp, Qh, Kf, Vf);
    hipLaunchKernelGGL(attn_kernel, dim3(B_ * T_ / 64), dim3(512), 0, stream,
                       Qh, Kf, Vf, F, out);
}